// Round 2
// baseline (1526.554 us; speedup 1.0000x reference)
//
#include <hip/hip_runtime.h>

#define BATCH   16
#define NPTS    4096
#define NPOINT  1024
#define NSAMPLE 32
#define NSITES  (BATCH*NPOINT*NSAMPLE)   // 524288

// ---------------- workspace layout (bytes) ----------------
// nxyz   : 0        (16*1024*3 f = 196608)
// gidx   : 196608   (16*1024*32 i = 2097152)
// psum   : 2293760  (256*64 f = 65536)
// psq    : 2359296  (65536)
// WF0    : 2424832  (288 f)   BF0: 2426880 (64 f)
// WF1    : 2427136  (1024 f)  BF1: 2431232 (64 f)
// WF2    : 2431488  (2048 f)  BF2: 2439680 (64 f)
// xbuf   : 2440192  (32*524288 f = 67108864)  -> total ~69.5 MB

// ============================================================
// 1. Farthest point sampling: one block per batch.
//    Exact numpy op order: d = ((dx*dx + dy*dy) + dz*dz), min, argmax(first).
//    (Bit-verified vs reference: Output 0 passes.)
// ============================================================
__global__ __launch_bounds__(256) void fps_kernel(
    const float* __restrict__ xyz,   // (B,3,N)
    float* __restrict__ nxyz,        // (B,S,3)
    float* __restrict__ out0)        // (B,3,S)  (output 0)
{
    __shared__ float sx[NPTS], sy[NPTS], sz[NPTS];
    __shared__ int   s_sel[NPOINT];
    __shared__ float red_val[2][4];
    __shared__ int   red_idx[2][4];

    const int b = blockIdx.x;
    const int t = threadIdx.x;
    const int wave = t >> 6, lane = t & 63;
    const float* xb = xyz + (size_t)b * 3 * NPTS;

    for (int i = t; i < NPTS; i += 256) {
        sx[i] = xb[i];
        sy[i] = xb[NPTS + i];
        sz[i] = xb[2*NPTS + i];
    }
    __syncthreads();

    float px[16], py[16], pz[16], dist[16];
    #pragma unroll
    for (int j = 0; j < 16; ++j) {
        const int i = t + 256 * j;
        px[j] = sx[i]; py[j] = sy[i]; pz[j] = sz[i];
        dist[j] = 1e10f;
    }

    int far = 0;
    for (int it = 0; it < NPOINT; ++it) {
        if (t == 0) s_sel[it] = far;
        const float cx = sx[far], cy = sy[far], cz = sz[far];
        float bval = -1.0f;
        int   bidx = 0;
        #pragma unroll
        for (int j = 0; j < 16; ++j) {
            const float dx = __fsub_rn(px[j], cx);
            const float dy = __fsub_rn(py[j], cy);
            const float dz = __fsub_rn(pz[j], cz);
            const float d  = __fadd_rn(__fadd_rn(__fmul_rn(dx,dx), __fmul_rn(dy,dy)),
                                       __fmul_rn(dz,dz));
            const float nd = fminf(dist[j], d);
            dist[j] = nd;
            if (nd > bval) { bval = nd; bidx = t + 256*j; }   // ascending idx -> first max kept
        }
        // wave butterfly argmax, tie -> smaller index
        #pragma unroll
        for (int off = 32; off >= 1; off >>= 1) {
            const float ov = __shfl_xor(bval, off);
            const int   oi = __shfl_xor(bidx, off);
            if (ov > bval || (ov == bval && oi < bidx)) { bval = ov; bidx = oi; }
        }
        const int par = it & 1;
        if (lane == 0) { red_val[par][wave] = bval; red_idx[par][wave] = bidx; }
        __syncthreads();
        bval = red_val[par][0]; bidx = red_idx[par][0];
        #pragma unroll
        for (int w = 1; w < 4; ++w) {
            const float ov = red_val[par][w]; const int oi = red_idx[par][w];
            if (ov > bval || (ov == bval && oi < bidx)) { bval = ov; bidx = oi; }
        }
        far = bidx;
    }
    __syncthreads();
    for (int s = t; s < NPOINT; s += 256) {
        const int id = s_sel[s];
        const float x = sx[id], y = sy[id], z = sz[id];
        nxyz[((size_t)b*NPOINT + s)*3 + 0] = x;
        nxyz[((size_t)b*NPOINT + s)*3 + 1] = y;
        nxyz[((size_t)b*NPOINT + s)*3 + 2] = z;
        out0[(size_t)b*3*NPOINT + 0*NPOINT + s] = x;
        out0[(size_t)b*3*NPOINT + 1*NPOINT + s] = y;
        out0[(size_t)b*3*NPOINT + 2*NPOINT + s] = z;
    }
}

// ============================================================
// 2. Ball query. Distance must bit-match the reference's einsum path:
//    dot via FMA chain (GEMM microkernel: acc = fma(a_k,b_k,acc), k ascending,
//    acc init 0 -> first term is a plain rounded product), ss/sn via plain
//    elementwise reduce, d = ((-2*dot) + ss) + sn with separate roundings.
// ============================================================
__global__ __launch_bounds__(256) void ball_kernel(
    const float* __restrict__ xyz, const float* __restrict__ nxyz,
    int* __restrict__ gidx)
{
    __shared__ float sx[NPTS], sy[NPTS], sz[NPTS];
    const int b  = blockIdx.x >> 4;
    const int sg = blockIdx.x & 15;
    const int t = threadIdx.x;
    const int wave = t >> 6, lane = t & 63;
    const float* xb = xyz + (size_t)b * 3 * NPTS;
    for (int i = t; i < NPTS; i += 256) {
        sx[i] = xb[i]; sy[i] = xb[NPTS+i]; sz[i] = xb[2*NPTS+i];
    }
    __syncthreads();
    const unsigned long long lt = (1ull << lane) - 1ull;

    for (int q = wave; q < 64; q += 4) {
        const int s = sg*64 + q;
        const size_t bs = (size_t)b*NPOINT + s;
        const float cx = nxyz[bs*3+0], cy = nxyz[bs*3+1], cz = nxyz[bs*3+2];
        const float ss = __fadd_rn(__fadd_rn(__fmul_rn(cx,cx), __fmul_rn(cy,cy)),
                                   __fmul_rn(cz,cz));
        int* out = gidx + bs*NSAMPLE;
        int cnt = 0;
        int firstIdx = NPTS;
        for (int ch = 0; ch < NPTS/64 && cnt < NSAMPLE; ++ch) {
            const int pi = ch*64 + lane;
            const float qx = sx[pi], qy = sy[pi], qz = sz[pi];
            // einsum dot: FMA chain, k ascending (x, then y, then z)
            const float dot = fmaf(cz, qz, fmaf(cy, qy, __fmul_rn(cx, qx)));
            const float sn  = __fadd_rn(__fadd_rn(__fmul_rn(qx,qx), __fmul_rn(qy,qy)),
                                        __fmul_rn(qz,qz));
            const float d   = __fadd_rn(__fadd_rn(__fmul_rn(-2.0f,dot), ss), sn);
            const bool pred = !(d > 0.04f);
            const unsigned long long m = __ballot(pred);
            if (pred) {
                const int pos = cnt + __popcll(m & lt);
                if (pos == 0) firstIdx = pi;
                if (pos < NSAMPLE) out[pos] = pi;
            }
            cnt += (int)__popcll(m);
        }
        if (cnt < NSAMPLE) {
            #pragma unroll
            for (int off = 32; off >= 1; off >>= 1) {
                const int oi = __shfl_xor(firstIdx, off);
                firstIdx = (oi < firstIdx) ? oi : firstIdx;
            }
            for (int p = cnt + lane; p < NSAMPLE; p += 64) out[p] = firstIdx;
        }
    }
}

// ---------------- feature gather (9 ch per site) ----------------
__device__ __forceinline__ void gather_feat(
    const float* __restrict__ xyz, const float* __restrict__ pts,
    const int* __restrict__ gidx, const float* __restrict__ nxyz,
    int v, float4 f[9])
{
    const int site = v * 4;
    const int bs = site >> 5;
    const int b  = bs >> 10;
    const int4 idx = *reinterpret_cast<const int4*>(gidx + site);
    const float* xb = xyz + (size_t)b*3*NPTS;
    const float* pb = pts + (size_t)b*6*NPTS;
    const float cx = nxyz[(size_t)bs*3+0];
    const float cy = nxyz[(size_t)bs*3+1];
    const float cz = nxyz[(size_t)bs*3+2];
    f[0] = make_float4(xb[idx.x]-cx, xb[idx.y]-cx, xb[idx.z]-cx, xb[idx.w]-cx);
    f[1] = make_float4(xb[NPTS+idx.x]-cy, xb[NPTS+idx.y]-cy, xb[NPTS+idx.z]-cy, xb[NPTS+idx.w]-cy);
    f[2] = make_float4(xb[2*NPTS+idx.x]-cz, xb[2*NPTS+idx.y]-cz, xb[2*NPTS+idx.z]-cz, xb[2*NPTS+idx.w]-cz);
    #pragma unroll
    for (int c = 0; c < 6; ++c)
        f[3+c] = make_float4(pb[c*NPTS+idx.x], pb[c*NPTS+idx.y], pb[c*NPTS+idx.z], pb[c*NPTS+idx.w]);
}

// ============================================================
// 3. Layer-0 stats: raw conv0 output sum/sumsq per channel, per-block partials
// ============================================================
__global__ __launch_bounds__(256) void stats0_kernel(
    const float* __restrict__ xyz, const float* __restrict__ pts,
    const int* __restrict__ gidx, const float* __restrict__ nxyz,
    const float* __restrict__ W, const float* __restrict__ bias,
    float* __restrict__ psum, float* __restrict__ psq)
{
    const int t = threadIdx.x;
    float acc[32], accq[32];
    #pragma unroll
    for (int o = 0; o < 32; ++o) { acc[o] = 0.f; accq[o] = 0.f; }
    const int stride = 256 * gridDim.x;
    for (int v = blockIdx.x*256 + t; v < NSITES/4; v += stride) {
        float4 f[9];
        gather_feat(xyz, pts, gidx, nxyz, v, f);
        #pragma unroll
        for (int o = 0; o < 32; ++o) {
            const float bb = bias[o];
            float4 y = make_float4(bb,bb,bb,bb);
            #pragma unroll
            for (int c = 0; c < 9; ++c) {
                const float w = W[o*9+c];
                y.x = fmaf(w, f[c].x, y.x); y.y = fmaf(w, f[c].y, y.y);
                y.z = fmaf(w, f[c].z, y.z); y.w = fmaf(w, f[c].w, y.w);
            }
            acc[o]  += (y.x + y.y) + (y.z + y.w);
            accq[o] += (y.x*y.x + y.y*y.y) + (y.z*y.z + y.w*y.w);
        }
    }
    __shared__ float ls[4][32], lq[4][32];
    const int wave = t>>6, lane = t&63;
    #pragma unroll
    for (int o = 0; o < 32; ++o) {
        float s1 = acc[o], q1 = accq[o];
        #pragma unroll
        for (int off = 32; off >= 1; off >>= 1) {
            s1 += __shfl_xor(s1, off);
            q1 += __shfl_xor(q1, off);
        }
        if (lane == 0) { ls[wave][o] = s1; lq[wave][o] = q1; }
    }
    __syncthreads();
    if (t < 32) {
        psum[blockIdx.x*64 + t] = (ls[0][t]+ls[1][t]) + (ls[2][t]+ls[3][t]);
        psq [blockIdx.x*64 + t] = (lq[0][t]+lq[1][t]) + (lq[2][t]+lq[3][t]);
    }
}

// ============================================================
// 4. Fold: deterministic partial-sum reduce -> mean/var -> fold BN into W,b
// ============================================================
__global__ void fold_kernel(
    const float* __restrict__ W, const float* __restrict__ bias,
    const float* __restrict__ g, const float* __restrict__ be,
    const float* __restrict__ psum, const float* __restrict__ psq,
    float* __restrict__ Wf, float* __restrict__ bf,
    int Cin, int Cout)
{
    __shared__ float a_sh[64];
    const int t = threadIdx.x;
    if (t < Cout) {
        float s = 0.f, q = 0.f;
        for (int i = 0; i < 256; ++i) { s += psum[i*64 + t]; q += psq[i*64 + t]; }
        const float invn = 1.0f / (float)NSITES;
        const float m = s * invn;
        float v2 = q * invn - m*m;
        v2 = fmaxf(v2, 0.f);
        const float rs = rsqrtf(v2 + 1e-5f);
        const float a = g[t] * rs;
        a_sh[t] = a;
        bf[t] = fmaf(bias[t] - m, a, be[t]);
    }
    __syncthreads();
    for (int i = t; i < Cout*Cin; i += blockDim.x)
        Wf[i] = W[i] * a_sh[i / Cin];
}

// ============================================================
// 5. Layer-0 apply: gather -> folded conv -> relu -> xbuf (32, NSITES)
// ============================================================
__global__ __launch_bounds__(256) void apply0_kernel(
    const float* __restrict__ xyz, const float* __restrict__ pts,
    const int* __restrict__ gidx, const float* __restrict__ nxyz,
    const float* __restrict__ Wf, const float* __restrict__ bf,
    float* __restrict__ xout)
{
    const int v = blockIdx.x*256 + threadIdx.x;   // exactly NSITES/4 threads
    const int site = v * 4;
    float4 f[9];
    gather_feat(xyz, pts, gidx, nxyz, v, f);
    #pragma unroll
    for (int o = 0; o < 32; ++o) {
        const float bb = bf[o];
        float4 y = make_float4(bb,bb,bb,bb);
        #pragma unroll
        for (int c = 0; c < 9; ++c) {
            const float w = Wf[o*9+c];
            y.x = fmaf(w, f[c].x, y.x); y.y = fmaf(w, f[c].y, y.y);
            y.z = fmaf(w, f[c].z, y.z); y.w = fmaf(w, f[c].w, y.w);
        }
        y.x = fmaxf(y.x, 0.f); y.y = fmaxf(y.y, 0.f);
        y.z = fmaxf(y.z, 0.f); y.w = fmaxf(y.w, 0.f);
        *reinterpret_cast<float4*>(xout + (size_t)o*NSITES + site) = y;
    }
}

// ============================================================
// 6. Stats over x-input conv (layers 1 & 2); blockIdx.y picks channel group
// ============================================================
template<int CIN, int COUT>
__global__ __launch_bounds__(256) void stats_x_kernel(
    const float* __restrict__ x, const float* __restrict__ W,
    const float* __restrict__ bias,
    float* __restrict__ psum, float* __restrict__ psq)
{
    const int t = threadIdx.x;
    const int coff = blockIdx.y * COUT;
    float acc[COUT], accq[COUT];
    #pragma unroll
    for (int o = 0; o < COUT; ++o) { acc[o] = 0.f; accq[o] = 0.f; }
    const int stride = 256 * gridDim.x;
    for (int v = blockIdx.x*256 + t; v < NSITES/4; v += stride) {
        const int site = v * 4;
        float4 in[CIN];
        #pragma unroll
        for (int c = 0; c < CIN; ++c)
            in[c] = *reinterpret_cast<const float4*>(x + (size_t)c*NSITES + site);
        #pragma unroll
        for (int o = 0; o < COUT; ++o) {
            const float bb = bias[coff + o];
            float4 y = make_float4(bb,bb,bb,bb);
            #pragma unroll
            for (int c = 0; c < CIN; ++c) {
                const float w = W[(coff+o)*CIN + c];
                y.x = fmaf(w, in[c].x, y.x); y.y = fmaf(w, in[c].y, y.y);
                y.z = fmaf(w, in[c].z, y.z); y.w = fmaf(w, in[c].w, y.w);
            }
            acc[o]  += (y.x + y.y) + (y.z + y.w);
            accq[o] += (y.x*y.x + y.y*y.y) + (y.z*y.z + y.w*y.w);
        }
    }
    __shared__ float ls[4][COUT], lq[4][COUT];
    const int wave = t>>6, lane = t&63;
    #pragma unroll
    for (int o = 0; o < COUT; ++o) {
        float s1 = acc[o], q1 = accq[o];
        #pragma unroll
        for (int off = 32; off >= 1; off >>= 1) {
            s1 += __shfl_xor(s1, off);
            q1 += __shfl_xor(q1, off);
        }
        if (lane == 0) { ls[wave][o] = s1; lq[wave][o] = q1; }
    }
    __syncthreads();
    if (t < COUT) {
        psum[blockIdx.x*64 + coff + t] = (ls[0][t]+ls[1][t]) + (ls[2][t]+ls[3][t]);
        psq [blockIdx.x*64 + coff + t] = (lq[0][t]+lq[1][t]) + (lq[2][t]+lq[3][t]);
    }
}

// ============================================================
// 7. Apply folded conv + relu, in-place capable (x may alias xout; all loads
//    precede stores and each thread owns its 4 sites exclusively)
// ============================================================
template<int CIN, int COUT>
__global__ __launch_bounds__(256) void apply_x_kernel(
    const float* x, float* xout,
    const float* __restrict__ Wf, const float* __restrict__ bf)
{
    const int v = blockIdx.x*256 + threadIdx.x;
    const int site = v * 4;
    float4 in[CIN];
    #pragma unroll
    for (int c = 0; c < CIN; ++c)
        in[c] = *reinterpret_cast<const float4*>(x + (size_t)c*NSITES + site);
    #pragma unroll
    for (int o = 0; o < COUT; ++o) {
        const float bb = bf[o];
        float4 y = make_float4(bb,bb,bb,bb);
        #pragma unroll
        for (int c = 0; c < CIN; ++c) {
            const float w = Wf[o*CIN+c];
            y.x = fmaf(w, in[c].x, y.x); y.y = fmaf(w, in[c].y, y.y);
            y.z = fmaf(w, in[c].z, y.z); y.w = fmaf(w, in[c].w, y.w);
        }
        y.x = fmaxf(y.x, 0.f); y.y = fmaxf(y.y, 0.f);
        y.z = fmaxf(y.z, 0.f); y.w = fmaxf(y.w, 0.f);
        *reinterpret_cast<float4*>(xout + (size_t)o*NSITES + site) = y;
    }
}

// ============================================================
// 8. Layer-2 apply + max over k: lane=site(k), loop o=0..63, butterfly max
//    within 32-lane halves (one wave = 2 (b,s) groups).
// ============================================================
__global__ __launch_bounds__(256) void apply2max_kernel(
    const float* __restrict__ x, const float* __restrict__ Wf,
    const float* __restrict__ bf, float* __restrict__ outp)   // (B,64,S)
{
    const int gt = blockIdx.x*256 + threadIdx.x;
    const int wv = gt >> 6;
    const int lane = gt & 63;
    const int base = wv * 64;
    float in[32];
    #pragma unroll
    for (int c = 0; c < 32; ++c)
        in[c] = x[(size_t)c*NSITES + base + lane];
    const int bs = (base + lane) >> 5;
    const int b = bs >> 10, s = bs & 1023;
    float* dst = outp + (size_t)b*64*NPOINT + s;
    for (int o = 0; o < 64; ++o) {
        float y = bf[o];
        #pragma unroll
        for (int c = 0; c < 32; ++c)
            y = fmaf(Wf[o*32+c], in[c], y);
        y = fmaxf(y, 0.f);
        #pragma unroll
        for (int off = 16; off >= 1; off >>= 1)
            y = fmaxf(y, __shfl_xor(y, off));
        if ((lane & 31) == 0)
            dst[(size_t)o*NPOINT] = y;
    }
}

// ============================================================
extern "C" void kernel_launch(void* const* d_in, const int* in_sizes, int n_in,
                              void* d_out, int out_size, void* d_ws, size_t ws_size,
                              hipStream_t stream) {
    (void)in_sizes; (void)n_in; (void)out_size; (void)ws_size;
    const float* xyz = (const float*)d_in[0];
    const float* pts = (const float*)d_in[1];
    const float* W0  = (const float*)d_in[2];
    const float* b0  = (const float*)d_in[3];
    const float* g0  = (const float*)d_in[4];
    const float* be0 = (const float*)d_in[5];
    const float* W1  = (const float*)d_in[6];
    const float* b1  = (const float*)d_in[7];
    const float* g1  = (const float*)d_in[8];
    const float* be1 = (const float*)d_in[9];
    const float* W2  = (const float*)d_in[10];
    const float* b2  = (const float*)d_in[11];
    const float* g2  = (const float*)d_in[12];
    const float* be2 = (const float*)d_in[13];
    float* out = (float*)d_out;
    char* ws = (char*)d_ws;
    float* nxyz = (float*)(ws + 0);
    int*   gidx = (int*)  (ws + 196608);
    float* psum = (float*)(ws + 2293760);
    float* psq  = (float*)(ws + 2359296);
    float* WF0  = (float*)(ws + 2424832);
    float* BF0  = (float*)(ws + 2426880);
    float* WF1  = (float*)(ws + 2427136);
    float* BF1  = (float*)(ws + 2431232);
    float* WF2  = (float*)(ws + 2431488);
    float* BF2  = (float*)(ws + 2439680);
    float* xbuf = (float*)(ws + 2440192);

    fps_kernel <<<16,  256, 0, stream>>>(xyz, nxyz, out);
    ball_kernel<<<256, 256, 0, stream>>>(xyz, nxyz, gidx);

    stats0_kernel<<<256, 256, 0, stream>>>(xyz, pts, gidx, nxyz, W0, b0, psum, psq);
    fold_kernel<<<1, 256, 0, stream>>>(W0, b0, g0, be0, psum, psq, WF0, BF0, 9, 32);
    apply0_kernel<<<512, 256, 0, stream>>>(xyz, pts, gidx, nxyz, WF0, BF0, xbuf);

    stats_x_kernel<32,32><<<dim3(256,1), 256, 0, stream>>>(xbuf, W1, b1, psum, psq);
    fold_kernel<<<1, 256, 0, stream>>>(W1, b1, g1, be1, psum, psq, WF1, BF1, 32, 32);
    apply_x_kernel<32,32><<<512, 256, 0, stream>>>(xbuf, xbuf, WF1, BF1);

    stats_x_kernel<32,32><<<dim3(256,2), 256, 0, stream>>>(xbuf, W2, b2, psum, psq);
    fold_kernel<<<1, 256, 0, stream>>>(W2, b2, g2, be2, psum, psq, WF2, BF2, 32, 64);
    apply2max_kernel<<<2048, 256, 0, stream>>>(xbuf, WF2, BF2, out + 49152);
}

// Round 3
// 1171.699 us; speedup vs baseline: 1.3029x; 1.3029x over previous
//
#include <hip/hip_runtime.h>

#define BATCH   16
#define NPTS    4096
#define NPOINT  1024
#define NSAMPLE 32
#define NSITES  (BATCH*NPOINT*NSAMPLE)   // 524288

// ---------------- workspace layout (bytes) ----------------
// nxyz   : 0        (16*1024*3 f = 196608)
// gidx   : 196608   (16*1024*32 i = 2097152)
// psum   : 2293760  (256*64 f = 65536)
// psq    : 2359296  (65536)
// WF0    : 2424832  (288 f)   BF0: 2426880 (64 f)
// WF1    : 2427136  (1024 f)  BF1: 2431232 (64 f)
// WF2    : 2431488  (2048 f)  BF2: 2439680 (64 f)
// xbuf   : 2440192  (32*524288 f = 67108864)  -> total ~69.5 MB

// ============================================================
// 1. Farthest point sampling: one block per batch, 16 pts/thread in REGISTERS.
//    launch_bounds(256,1): allow full VGPR budget (round-2 profile showed the
//    compiler capped at 68 VGPRs and rematerialized coords from LDS every
//    iteration -> 3x slowdown). Argmax via packed u64 (dist_bits<<32 | ~idx):
//    d>=0 so float-bit compare is monotone; ~idx = first-index tie-break.
//    Distance arithmetic bit-matches reference (validated round 2).
// ============================================================
__global__ __launch_bounds__(256, 1) void fps_kernel(
    const float* __restrict__ xyz,   // (B,3,N)
    float* __restrict__ nxyz,        // (B,S,3)
    float* __restrict__ out0)        // (B,3,S)  (output 0)
{
    __shared__ float sx[NPTS], sy[NPTS], sz[NPTS];
    __shared__ int   s_sel[NPOINT];
    __shared__ unsigned long long red[2][4];

    const int b = blockIdx.x;
    const int t = threadIdx.x;
    const int wave = t >> 6, lane = t & 63;
    const float* xb = xyz + (size_t)b * 3 * NPTS;

    for (int i = t; i < NPTS; i += 256) {
        sx[i] = xb[i];
        sy[i] = xb[NPTS + i];
        sz[i] = xb[2*NPTS + i];
    }
    __syncthreads();

    float px[16], py[16], pz[16], dist[16];
    unsigned int nidx[16];
    #pragma unroll
    for (int j = 0; j < 16; ++j) {
        const int i = t + 256 * j;
        px[j] = sx[i]; py[j] = sy[i]; pz[j] = sz[i];
        dist[j] = 1e10f;
        nidx[j] = ~(unsigned int)i;
    }

    int far = 0;
    for (int it = 0; it < NPOINT; ++it) {
        if (t == 0) s_sel[it] = far;
        const float cx = sx[far], cy = sy[far], cz = sz[far];
        unsigned long long k[16];
        #pragma unroll
        for (int j = 0; j < 16; ++j) {
            const float dx = __fsub_rn(px[j], cx);
            const float dy = __fsub_rn(py[j], cy);
            const float dz = __fsub_rn(pz[j], cz);
            const float d  = __fadd_rn(__fadd_rn(__fmul_rn(dx,dx), __fmul_rn(dy,dy)),
                                       __fmul_rn(dz,dz));
            const float nd = fminf(dist[j], d);
            dist[j] = nd;
            k[j] = ((unsigned long long)__float_as_uint(nd) << 32) | nidx[j];
        }
        // 4-level tree over the 16 per-thread keys
        #pragma unroll
        for (int w = 8; w >= 1; w >>= 1)
            #pragma unroll
            for (int j = 0; j < 16; ++j)
                if (j < w) k[j] = (k[j+w] > k[j]) ? k[j+w] : k[j];
        unsigned long long best = k[0];
        // 6-level wave butterfly
        #pragma unroll
        for (int off = 32; off >= 1; off >>= 1) {
            const unsigned long long o = __shfl_xor(best, off);
            best = (o > best) ? o : best;
        }
        const int par = it & 1;
        if (lane == 0) red[par][wave] = best;
        __syncthreads();
        unsigned long long b0 = red[par][0];
        const unsigned long long b1 = red[par][1];
        const unsigned long long b2 = red[par][2];
        const unsigned long long b3 = red[par][3];
        unsigned long long m01 = (b1 > b0) ? b1 : b0;
        const unsigned long long m23 = (b3 > b2) ? b3 : b2;
        if (m23 > m01) m01 = m23;
        far = (int)(~(unsigned int)m01 & 0xFFFFu);
    }
    __syncthreads();
    for (int s = t; s < NPOINT; s += 256) {
        const int id = s_sel[s];
        const float x = sx[id], y = sy[id], z = sz[id];
        nxyz[((size_t)b*NPOINT + s)*3 + 0] = x;
        nxyz[((size_t)b*NPOINT + s)*3 + 1] = y;
        nxyz[((size_t)b*NPOINT + s)*3 + 2] = z;
        out0[(size_t)b*3*NPOINT + 0*NPOINT + s] = x;
        out0[(size_t)b*3*NPOINT + 1*NPOINT + s] = y;
        out0[(size_t)b*3*NPOINT + 2*NPOINT + s] = z;
    }
}

// ============================================================
// 2. Ball query. Distance must bit-match the reference's einsum path:
//    dot via FMA chain (GEMM microkernel: acc = fma(a_k,b_k,acc), k ascending,
//    acc init 0 -> first term is a plain rounded product), ss/sn via plain
//    elementwise reduce, d = ((-2*dot) + ss) + sn with separate roundings.
//    (Validated: passed round 2.)
// ============================================================
__global__ __launch_bounds__(256) void ball_kernel(
    const float* __restrict__ xyz, const float* __restrict__ nxyz,
    int* __restrict__ gidx)
{
    __shared__ float sx[NPTS], sy[NPTS], sz[NPTS];
    const int b  = blockIdx.x >> 4;
    const int sg = blockIdx.x & 15;
    const int t = threadIdx.x;
    const int wave = t >> 6, lane = t & 63;
    const float* xb = xyz + (size_t)b * 3 * NPTS;
    for (int i = t; i < NPTS; i += 256) {
        sx[i] = xb[i]; sy[i] = xb[NPTS+i]; sz[i] = xb[2*NPTS+i];
    }
    __syncthreads();
    const unsigned long long lt = (1ull << lane) - 1ull;

    for (int q = wave; q < 64; q += 4) {
        const int s = sg*64 + q;
        const size_t bs = (size_t)b*NPOINT + s;
        const float cx = nxyz[bs*3+0], cy = nxyz[bs*3+1], cz = nxyz[bs*3+2];
        const float ss = __fadd_rn(__fadd_rn(__fmul_rn(cx,cx), __fmul_rn(cy,cy)),
                                   __fmul_rn(cz,cz));
        int* out = gidx + bs*NSAMPLE;
        int cnt = 0;
        int firstIdx = NPTS;
        for (int ch = 0; ch < NPTS/64 && cnt < NSAMPLE; ++ch) {
            const int pi = ch*64 + lane;
            const float qx = sx[pi], qy = sy[pi], qz = sz[pi];
            const float dot = fmaf(cz, qz, fmaf(cy, qy, __fmul_rn(cx, qx)));
            const float sn  = __fadd_rn(__fadd_rn(__fmul_rn(qx,qx), __fmul_rn(qy,qy)),
                                        __fmul_rn(qz,qz));
            const float d   = __fadd_rn(__fadd_rn(__fmul_rn(-2.0f,dot), ss), sn);
            const bool pred = !(d > 0.04f);
            const unsigned long long m = __ballot(pred);
            if (pred) {
                const int pos = cnt + __popcll(m & lt);
                if (pos == 0) firstIdx = pi;
                if (pos < NSAMPLE) out[pos] = pi;
            }
            cnt += (int)__popcll(m);
        }
        if (cnt < NSAMPLE) {
            #pragma unroll
            for (int off = 32; off >= 1; off >>= 1) {
                const int oi = __shfl_xor(firstIdx, off);
                firstIdx = (oi < firstIdx) ? oi : firstIdx;
            }
            for (int p = cnt + lane; p < NSAMPLE; p += 64) out[p] = firstIdx;
        }
    }
}

// ---------------- feature gather (9 ch per site) ----------------
__device__ __forceinline__ void gather_feat(
    const float* __restrict__ xyz, const float* __restrict__ pts,
    const int* __restrict__ gidx, const float* __restrict__ nxyz,
    int v, float4 f[9])
{
    const int site = v * 4;
    const int bs = site >> 5;
    const int b  = bs >> 10;
    const int4 idx = *reinterpret_cast<const int4*>(gidx + site);
    const float* xb = xyz + (size_t)b*3*NPTS;
    const float* pb = pts + (size_t)b*6*NPTS;
    const float cx = nxyz[(size_t)bs*3+0];
    const float cy = nxyz[(size_t)bs*3+1];
    const float cz = nxyz[(size_t)bs*3+2];
    f[0] = make_float4(xb[idx.x]-cx, xb[idx.y]-cx, xb[idx.z]-cx, xb[idx.w]-cx);
    f[1] = make_float4(xb[NPTS+idx.x]-cy, xb[NPTS+idx.y]-cy, xb[NPTS+idx.z]-cy, xb[NPTS+idx.w]-cy);
    f[2] = make_float4(xb[2*NPTS+idx.x]-cz, xb[2*NPTS+idx.y]-cz, xb[2*NPTS+idx.z]-cz, xb[2*NPTS+idx.w]-cz);
    #pragma unroll
    for (int c = 0; c < 6; ++c)
        f[3+c] = make_float4(pb[c*NPTS+idx.x], pb[c*NPTS+idx.y], pb[c*NPTS+idx.z], pb[c*NPTS+idx.w]);
}

// ============================================================
// 3. Layer-0 stats: raw conv0 output sum/sumsq per channel, per-block partials
// ============================================================
__global__ __launch_bounds__(256) void stats0_kernel(
    const float* __restrict__ xyz, const float* __restrict__ pts,
    const int* __restrict__ gidx, const float* __restrict__ nxyz,
    const float* __restrict__ W, const float* __restrict__ bias,
    float* __restrict__ psum, float* __restrict__ psq)
{
    const int t = threadIdx.x;
    float acc[32], accq[32];
    #pragma unroll
    for (int o = 0; o < 32; ++o) { acc[o] = 0.f; accq[o] = 0.f; }
    const int stride = 256 * gridDim.x;
    for (int v = blockIdx.x*256 + t; v < NSITES/4; v += stride) {
        float4 f[9];
        gather_feat(xyz, pts, gidx, nxyz, v, f);
        #pragma unroll
        for (int o = 0; o < 32; ++o) {
            const float bb = bias[o];
            float4 y = make_float4(bb,bb,bb,bb);
            #pragma unroll
            for (int c = 0; c < 9; ++c) {
                const float w = W[o*9+c];
                y.x = fmaf(w, f[c].x, y.x); y.y = fmaf(w, f[c].y, y.y);
                y.z = fmaf(w, f[c].z, y.z); y.w = fmaf(w, f[c].w, y.w);
            }
            acc[o]  += (y.x + y.y) + (y.z + y.w);
            accq[o] += (y.x*y.x + y.y*y.y) + (y.z*y.z + y.w*y.w);
        }
    }
    __shared__ float ls[4][32], lq[4][32];
    const int wave = t>>6, lane = t&63;
    #pragma unroll
    for (int o = 0; o < 32; ++o) {
        float s1 = acc[o], q1 = accq[o];
        #pragma unroll
        for (int off = 32; off >= 1; off >>= 1) {
            s1 += __shfl_xor(s1, off);
            q1 += __shfl_xor(q1, off);
        }
        if (lane == 0) { ls[wave][o] = s1; lq[wave][o] = q1; }
    }
    __syncthreads();
    if (t < 32) {
        psum[blockIdx.x*64 + t] = (ls[0][t]+ls[1][t]) + (ls[2][t]+ls[3][t]);
        psq [blockIdx.x*64 + t] = (lq[0][t]+lq[1][t]) + (lq[2][t]+lq[3][t]);
    }
}

// ============================================================
// 4. Fold: deterministic partial-sum reduce -> mean/var -> fold BN into W,b
// ============================================================
__global__ void fold_kernel(
    const float* __restrict__ W, const float* __restrict__ bias,
    const float* __restrict__ g, const float* __restrict__ be,
    const float* __restrict__ psum, const float* __restrict__ psq,
    float* __restrict__ Wf, float* __restrict__ bf,
    int Cin, int Cout)
{
    __shared__ float a_sh[64];
    const int t = threadIdx.x;
    if (t < Cout) {
        float s = 0.f, q = 0.f;
        for (int i = 0; i < 256; ++i) { s += psum[i*64 + t]; q += psq[i*64 + t]; }
        const float invn = 1.0f / (float)NSITES;
        const float m = s * invn;
        float v2 = q * invn - m*m;
        v2 = fmaxf(v2, 0.f);
        const float rs = rsqrtf(v2 + 1e-5f);
        const float a = g[t] * rs;
        a_sh[t] = a;
        bf[t] = fmaf(bias[t] - m, a, be[t]);
    }
    __syncthreads();
    for (int i = t; i < Cout*Cin; i += blockDim.x)
        Wf[i] = W[i] * a_sh[i / Cin];
}

// ============================================================
// 5. Layer-0 apply: gather -> folded conv -> relu -> xbuf (32, NSITES)
// ============================================================
__global__ __launch_bounds__(256) void apply0_kernel(
    const float* __restrict__ xyz, const float* __restrict__ pts,
    const int* __restrict__ gidx, const float* __restrict__ nxyz,
    const float* __restrict__ Wf, const float* __restrict__ bf,
    float* __restrict__ xout)
{
    const int v = blockIdx.x*256 + threadIdx.x;   // exactly NSITES/4 threads
    const int site = v * 4;
    float4 f[9];
    gather_feat(xyz, pts, gidx, nxyz, v, f);
    #pragma unroll
    for (int o = 0; o < 32; ++o) {
        const float bb = bf[o];
        float4 y = make_float4(bb,bb,bb,bb);
        #pragma unroll
        for (int c = 0; c < 9; ++c) {
            const float w = Wf[o*9+c];
            y.x = fmaf(w, f[c].x, y.x); y.y = fmaf(w, f[c].y, y.y);
            y.z = fmaf(w, f[c].z, y.z); y.w = fmaf(w, f[c].w, y.w);
        }
        y.x = fmaxf(y.x, 0.f); y.y = fmaxf(y.y, 0.f);
        y.z = fmaxf(y.z, 0.f); y.w = fmaxf(y.w, 0.f);
        *reinterpret_cast<float4*>(xout + (size_t)o*NSITES + site) = y;
    }
}

// ============================================================
// 6. Stats over x-input conv (layers 1 & 2); blockIdx.y picks channel group
// ============================================================
template<int CIN, int COUT>
__global__ __launch_bounds__(256) void stats_x_kernel(
    const float* __restrict__ x, const float* __restrict__ W,
    const float* __restrict__ bias,
    float* __restrict__ psum, float* __restrict__ psq)
{
    const int t = threadIdx.x;
    const int coff = blockIdx.y * COUT;
    float acc[COUT], accq[COUT];
    #pragma unroll
    for (int o = 0; o < COUT; ++o) { acc[o] = 0.f; accq[o] = 0.f; }
    const int stride = 256 * gridDim.x;
    for (int v = blockIdx.x*256 + t; v < NSITES/4; v += stride) {
        const int site = v * 4;
        float4 in[CIN];
        #pragma unroll
        for (int c = 0; c < CIN; ++c)
            in[c] = *reinterpret_cast<const float4*>(x + (size_t)c*NSITES + site);
        #pragma unroll
        for (int o = 0; o < COUT; ++o) {
            const float bb = bias[coff + o];
            float4 y = make_float4(bb,bb,bb,bb);
            #pragma unroll
            for (int c = 0; c < CIN; ++c) {
                const float w = W[(coff+o)*CIN + c];
                y.x = fmaf(w, in[c].x, y.x); y.y = fmaf(w, in[c].y, y.y);
                y.z = fmaf(w, in[c].z, y.z); y.w = fmaf(w, in[c].w, y.w);
            }
            acc[o]  += (y.x + y.y) + (y.z + y.w);
            accq[o] += (y.x*y.x + y.y*y.y) + (y.z*y.z + y.w*y.w);
        }
    }
    __shared__ float ls[4][COUT], lq[4][COUT];
    const int wave = t>>6, lane = t&63;
    #pragma unroll
    for (int o = 0; o < COUT; ++o) {
        float s1 = acc[o], q1 = accq[o];
        #pragma unroll
        for (int off = 32; off >= 1; off >>= 1) {
            s1 += __shfl_xor(s1, off);
            q1 += __shfl_xor(q1, off);
        }
        if (lane == 0) { ls[wave][o] = s1; lq[wave][o] = q1; }
    }
    __syncthreads();
    if (t < COUT) {
        psum[blockIdx.x*64 + coff + t] = (ls[0][t]+ls[1][t]) + (ls[2][t]+ls[3][t]);
        psq [blockIdx.x*64 + coff + t] = (lq[0][t]+lq[1][t]) + (lq[2][t]+lq[3][t]);
    }
}

// ============================================================
// 7. Apply folded conv + relu, in-place capable (x may alias xout; all loads
//    precede stores and each thread owns its 4 sites exclusively)
// ============================================================
template<int CIN, int COUT>
__global__ __launch_bounds__(256) void apply_x_kernel(
    const float* x, float* xout,
    const float* __restrict__ Wf, const float* __restrict__ bf)
{
    const int v = blockIdx.x*256 + threadIdx.x;
    const int site = v * 4;
    float4 in[CIN];
    #pragma unroll
    for (int c = 0; c < CIN; ++c)
        in[c] = *reinterpret_cast<const float4*>(x + (size_t)c*NSITES + site);
    #pragma unroll
    for (int o = 0; o < COUT; ++o) {
        const float bb = bf[o];
        float4 y = make_float4(bb,bb,bb,bb);
        #pragma unroll
        for (int c = 0; c < CIN; ++c) {
            const float w = Wf[o*CIN+c];
            y.x = fmaf(w, in[c].x, y.x); y.y = fmaf(w, in[c].y, y.y);
            y.z = fmaf(w, in[c].z, y.z); y.w = fmaf(w, in[c].w, y.w);
        }
        y.x = fmaxf(y.x, 0.f); y.y = fmaxf(y.y, 0.f);
        y.z = fmaxf(y.z, 0.f); y.w = fmaxf(y.w, 0.f);
        *reinterpret_cast<float4*>(xout + (size_t)o*NSITES + site) = y;
    }
}

// ============================================================
// 8. Layer-2 apply + max over k: lane=site(k), loop o=0..63, butterfly max
//    within 32-lane halves (one wave = 2 (b,s) groups).
// ============================================================
__global__ __launch_bounds__(256) void apply2max_kernel(
    const float* __restrict__ x, const float* __restrict__ Wf,
    const float* __restrict__ bf, float* __restrict__ outp)   // (B,64,S)
{
    const int gt = blockIdx.x*256 + threadIdx.x;
    const int wv = gt >> 6;
    const int lane = gt & 63;
    const int base = wv * 64;
    float in[32];
    #pragma unroll
    for (int c = 0; c < 32; ++c)
        in[c] = x[(size_t)c*NSITES + base + lane];
    const int bs = (base + lane) >> 5;
    const int b = bs >> 10, s = bs & 1023;
    float* dst = outp + (size_t)b*64*NPOINT + s;
    for (int o = 0; o < 64; ++o) {
        float y = bf[o];
        #pragma unroll
        for (int c = 0; c < 32; ++c)
            y = fmaf(Wf[o*32+c], in[c], y);
        y = fmaxf(y, 0.f);
        #pragma unroll
        for (int off = 16; off >= 1; off >>= 1)
            y = fmaxf(y, __shfl_xor(y, off));
        if ((lane & 31) == 0)
            dst[(size_t)o*NPOINT] = y;
    }
}

// ============================================================
extern "C" void kernel_launch(void* const* d_in, const int* in_sizes, int n_in,
                              void* d_out, int out_size, void* d_ws, size_t ws_size,
                              hipStream_t stream) {
    (void)in_sizes; (void)n_in; (void)out_size; (void)ws_size;
    const float* xyz = (const float*)d_in[0];
    const float* pts = (const float*)d_in[1];
    const float* W0  = (const float*)d_in[2];
    const float* b0  = (const float*)d_in[3];
    const float* g0  = (const float*)d_in[4];
    const float* be0 = (const float*)d_in[5];
    const float* W1  = (const float*)d_in[6];
    const float* b1  = (const float*)d_in[7];
    const float* g1  = (const float*)d_in[8];
    const float* be1 = (const float*)d_in[9];
    const float* W2  = (const float*)d_in[10];
    const float* b2  = (const float*)d_in[11];
    const float* g2  = (const float*)d_in[12];
    const float* be2 = (const float*)d_in[13];
    float* out = (float*)d_out;
    char* ws = (char*)d_ws;
    float* nxyz = (float*)(ws + 0);
    int*   gidx = (int*)  (ws + 196608);
    float* psum = (float*)(ws + 2293760);
    float* psq  = (float*)(ws + 2359296);
    float* WF0  = (float*)(ws + 2424832);
    float* BF0  = (float*)(ws + 2426880);
    float* WF1  = (float*)(ws + 2427136);
    float* BF1  = (float*)(ws + 2431232);
    float* WF2  = (float*)(ws + 2431488);
    float* BF2  = (float*)(ws + 2439680);
    float* xbuf = (float*)(ws + 2440192);

    fps_kernel <<<16,  256, 0, stream>>>(xyz, nxyz, out);
    ball_kernel<<<256, 256, 0, stream>>>(xyz, nxyz, gidx);

    stats0_kernel<<<256, 256, 0, stream>>>(xyz, pts, gidx, nxyz, W0, b0, psum, psq);
    fold_kernel<<<1, 256, 0, stream>>>(W0, b0, g0, be0, psum, psq, WF0, BF0, 9, 32);
    apply0_kernel<<<512, 256, 0, stream>>>(xyz, pts, gidx, nxyz, WF0, BF0, xbuf);

    stats_x_kernel<32,32><<<dim3(256,1), 256, 0, stream>>>(xbuf, W1, b1, psum, psq);
    fold_kernel<<<1, 256, 0, stream>>>(W1, b1, g1, be1, psum, psq, WF1, BF1, 32, 32);
    apply_x_kernel<32,32><<<512, 256, 0, stream>>>(xbuf, xbuf, WF1, BF1);

    stats_x_kernel<32,32><<<dim3(256,2), 256, 0, stream>>>(xbuf, W2, b2, psum, psq);
    fold_kernel<<<1, 256, 0, stream>>>(W2, b2, g2, be2, psum, psq, WF2, BF2, 32, 64);
    apply2max_kernel<<<2048, 256, 0, stream>>>(xbuf, WF2, BF2, out + 49152);
}

// Round 4
// 1100.250 us; speedup vs baseline: 1.3875x; 1.0649x over previous
//
#include <hip/hip_runtime.h>

#define BATCH   16
#define NPTS    4096
#define NPOINT  1024
#define NSAMPLE 32
#define NSITES  (BATCH*NPOINT*NSAMPLE)   // 524288

// ---------------- workspace layout (bytes) ----------------
// nxyz : 0        (196608)
// gidx : 196608   (2097152)
// psum : 2293760  (512*64*4 = 131072)
// psq  : 2424832  (131072)
// aff0 : 2555904  (128 f = 512)   aff = {a[64], c[64]}: act = relu(a*x+c)
// aff1 : 2556416  (512)
// aff2 : 2556928  (512)
// xbuf : 2557440  (64 MB)  -> total ~69.7 MB

// ============================================================
// 1. FPS: one block/batch, 512 threads, 8 CONTIGUOUS pts/thread in registers
//    (32 floats/thread fits any VGPR cap -> no remat/spill, unlike r2/r3).
//    Reduce: per-thread first-max tree (strict >), f32 value-only butterfly,
//    ballot -> lowest lane = smallest index (contiguous ownership), winner
//    packs (val,~idx) u64 -> LDS; 1 barrier; 8-way cross-wave butterfly.
//    Distance math bit-matches reference (validated rounds 2/3).
// ============================================================
__global__ __launch_bounds__(512, 1) void fps_kernel(
    const float* __restrict__ xyz,   // (B,3,N)
    float* __restrict__ nxyz,        // (B,S,3)
    float* __restrict__ out0)        // (B,3,S)
{
    __shared__ float sx[NPTS], sy[NPTS], sz[NPTS];
    __shared__ int   s_sel[NPOINT];
    __shared__ unsigned long long red[2][8];

    const int b = blockIdx.x;
    const int t = threadIdx.x;
    const int wave = t >> 6, lane = t & 63;
    const float* xb = xyz + (size_t)b * 3 * NPTS;

    for (int i = t; i < NPTS; i += 512) {
        sx[i] = xb[i]; sy[i] = xb[NPTS+i]; sz[i] = xb[2*NPTS+i];
    }
    __syncthreads();

    const int base = t * 8;
    float px[8], py[8], pz[8], dist[8];
    #pragma unroll
    for (int j = 0; j < 8; ++j) {
        px[j] = sx[base+j]; py[j] = sy[base+j]; pz[j] = sz[base+j];
        dist[j] = 1e10f;
    }

    int far = 0;
    for (int it = 0; it < NPOINT; ++it) {
        if (t == 0) s_sel[it] = far;
        const float cx = sx[far], cy = sy[far], cz = sz[far];
        float v[8];
        #pragma unroll
        for (int j = 0; j < 8; ++j) {
            const float dx = __fsub_rn(px[j], cx);
            const float dy = __fsub_rn(py[j], cy);
            const float dz = __fsub_rn(pz[j], cz);
            const float d  = __fadd_rn(__fadd_rn(__fmul_rn(dx,dx), __fmul_rn(dy,dy)),
                                       __fmul_rn(dz,dz));
            const float nd = fminf(dist[j], d);
            dist[j] = nd;
            v[j] = nd;
        }
        // per-thread first-max tree (strict > : earlier index wins ties)
        float mv0, mv1, mv2, mv3; int mi0, mi1, mi2, mi3;
        { bool c1 = v[1] > v[0]; mv0 = c1 ? v[1] : v[0]; mi0 = c1 ? 1 : 0; }
        { bool c1 = v[3] > v[2]; mv1 = c1 ? v[3] : v[2]; mi1 = c1 ? 3 : 2; }
        { bool c1 = v[5] > v[4]; mv2 = c1 ? v[5] : v[4]; mi2 = c1 ? 5 : 4; }
        { bool c1 = v[7] > v[6]; mv3 = c1 ? v[7] : v[6]; mi3 = c1 ? 7 : 6; }
        float nv0, nv1; int ni0, ni1;
        { bool c1 = mv1 > mv0; nv0 = c1 ? mv1 : mv0; ni0 = c1 ? mi1 : mi0; }
        { bool c1 = mv3 > mv2; nv1 = c1 ? mv3 : mv2; ni1 = c1 ? mi3 : mi2; }
        float bm; int bj;
        { bool c1 = nv1 > nv0; bm = c1 ? nv1 : nv0; bj = c1 ? ni1 : ni0; }
        // value-only wave butterfly
        float M = bm;
        #pragma unroll
        for (int off = 32; off >= 1; off >>= 1)
            M = fmaxf(M, __shfl_xor(M, off));
        // lowest lane with bm == M  == smallest index (contiguous ownership)
        const unsigned long long mask = __ballot(bm == M);
        const int wl = __ffsll(mask) - 1;
        const int par = it & 1;
        if (lane == wl) {
            const unsigned idxg = (unsigned)(base + bj);
            red[par][wave] = ((unsigned long long)__float_as_uint(M) << 32)
                             | (unsigned)(~idxg);
        }
        __syncthreads();
        unsigned long long k2 = red[par][lane & 7];
        #pragma unroll
        for (int off = 1; off <= 4; off <<= 1) {
            const unsigned long long o = __shfl_xor(k2, off);
            k2 = (o > k2) ? o : k2;
        }
        far = (int)((~(unsigned)k2) & (NPTS-1));
    }
    __syncthreads();
    for (int s = t; s < NPOINT; s += 512) {
        const int id = s_sel[s];
        const float x = sx[id], y = sy[id], z = sz[id];
        nxyz[((size_t)b*NPOINT + s)*3 + 0] = x;
        nxyz[((size_t)b*NPOINT + s)*3 + 1] = y;
        nxyz[((size_t)b*NPOINT + s)*3 + 2] = z;
        out0[(size_t)b*3*NPOINT + 0*NPOINT + s] = x;
        out0[(size_t)b*3*NPOINT + 1*NPOINT + s] = y;
        out0[(size_t)b*3*NPOINT + 2*NPOINT + s] = z;
    }
}

// ============================================================
// 2. Ball query (validated bit-exact round 2/3 — unchanged).
// ============================================================
__global__ __launch_bounds__(256) void ball_kernel(
    const float* __restrict__ xyz, const float* __restrict__ nxyz,
    int* __restrict__ gidx)
{
    __shared__ float sx[NPTS], sy[NPTS], sz[NPTS];
    const int b  = blockIdx.x >> 4;
    const int sg = blockIdx.x & 15;
    const int t = threadIdx.x;
    const int wave = t >> 6, lane = t & 63;
    const float* xb = xyz + (size_t)b * 3 * NPTS;
    for (int i = t; i < NPTS; i += 256) {
        sx[i] = xb[i]; sy[i] = xb[NPTS+i]; sz[i] = xb[2*NPTS+i];
    }
    __syncthreads();
    const unsigned long long lt = (1ull << lane) - 1ull;

    for (int q = wave; q < 64; q += 4) {
        const int s = sg*64 + q;
        const size_t bs = (size_t)b*NPOINT + s;
        const float cx = nxyz[bs*3+0], cy = nxyz[bs*3+1], cz = nxyz[bs*3+2];
        const float ss = __fadd_rn(__fadd_rn(__fmul_rn(cx,cx), __fmul_rn(cy,cy)),
                                   __fmul_rn(cz,cz));
        int* out = gidx + bs*NSAMPLE;
        int cnt = 0;
        int firstIdx = NPTS;
        for (int ch = 0; ch < NPTS/64 && cnt < NSAMPLE; ++ch) {
            const int pi = ch*64 + lane;
            const float qx = sx[pi], qy = sy[pi], qz = sz[pi];
            const float dot = fmaf(cz, qz, fmaf(cy, qy, __fmul_rn(cx, qx)));
            const float sn  = __fadd_rn(__fadd_rn(__fmul_rn(qx,qx), __fmul_rn(qy,qy)),
                                        __fmul_rn(qz,qz));
            const float d   = __fadd_rn(__fadd_rn(__fmul_rn(-2.0f,dot), ss), sn);
            const bool pred = !(d > 0.04f);
            const unsigned long long m = __ballot(pred);
            if (pred) {
                const int pos = cnt + __popcll(m & lt);
                if (pos == 0) firstIdx = pi;
                if (pos < NSAMPLE) out[pos] = pi;
            }
            cnt += (int)__popcll(m);
        }
        if (cnt < NSAMPLE) {
            #pragma unroll
            for (int off = 32; off >= 1; off >>= 1) {
                const int oi = __shfl_xor(firstIdx, off);
                firstIdx = (oi < firstIdx) ? oi : firstIdx;
            }
            for (int p = cnt + lane; p < NSAMPLE; p += 64) out[p] = firstIdx;
        }
    }
}

// ---------------- feature gather (9 ch per site) ----------------
__device__ __forceinline__ void gather_feat(
    const float* __restrict__ xyz, const float* __restrict__ pts,
    const int* __restrict__ gidx, const float* __restrict__ nxyz,
    int v, float4 f[9])
{
    const int site = v * 4;
    const int bs = site >> 5;
    const int b  = bs >> 10;
    const int4 idx = *reinterpret_cast<const int4*>(gidx + site);
    const float* xb = xyz + (size_t)b*3*NPTS;
    const float* pb = pts + (size_t)b*6*NPTS;
    const float cx = nxyz[(size_t)bs*3+0];
    const float cy = nxyz[(size_t)bs*3+1];
    const float cz = nxyz[(size_t)bs*3+2];
    f[0] = make_float4(xb[idx.x]-cx, xb[idx.y]-cx, xb[idx.z]-cx, xb[idx.w]-cx);
    f[1] = make_float4(xb[NPTS+idx.x]-cy, xb[NPTS+idx.y]-cy, xb[NPTS+idx.z]-cy, xb[NPTS+idx.w]-cy);
    f[2] = make_float4(xb[2*NPTS+idx.x]-cz, xb[2*NPTS+idx.y]-cz, xb[2*NPTS+idx.z]-cz, xb[2*NPTS+idx.w]-cz);
    #pragma unroll
    for (int c = 0; c < 6; ++c)
        f[3+c] = make_float4(pb[c*NPTS+idx.x], pb[c*NPTS+idx.y], pb[c*NPTS+idx.z], pb[c*NPTS+idx.w]);
}

// ============================================================
// 3. conv0: ONE gather pass -> raw conv0 (W0,b0) stored + stats partials.
//    (BN affine applied on-the-fly by the consumer.)
// ============================================================
__global__ __launch_bounds__(256) void conv0s_kernel(
    const float* __restrict__ xyz, const float* __restrict__ pts,
    const int* __restrict__ gidx, const float* __restrict__ nxyz,
    const float* __restrict__ W, const float* __restrict__ bias,
    float* __restrict__ xout, float* __restrict__ psum, float* __restrict__ psq)
{
    const int t = threadIdx.x;
    const int v = blockIdx.x*256 + t;        // 512 blocks -> v < 131072
    const int site = v * 4;
    float4 f[9];
    gather_feat(xyz, pts, gidx, nxyz, v, f);
    float acc[32], accq[32];
    #pragma unroll
    for (int o = 0; o < 32; ++o) {
        const float bb = bias[o];
        float4 y = make_float4(bb,bb,bb,bb);
        #pragma unroll
        for (int c = 0; c < 9; ++c) {
            const float w = W[o*9+c];
            y.x = fmaf(w, f[c].x, y.x); y.y = fmaf(w, f[c].y, y.y);
            y.z = fmaf(w, f[c].z, y.z); y.w = fmaf(w, f[c].w, y.w);
        }
        *reinterpret_cast<float4*>(xout + (size_t)o*NSITES + site) = y;  // RAW
        acc[o]  = (y.x + y.y) + (y.z + y.w);
        accq[o] = (y.x*y.x + y.y*y.y) + (y.z*y.z + y.w*y.w);
    }
    __shared__ float ls[4][32], lq[4][32];
    const int wave = t>>6, lane = t&63;
    #pragma unroll
    for (int o = 0; o < 32; ++o) {
        float s1 = acc[o], q1 = accq[o];
        #pragma unroll
        for (int off = 32; off >= 1; off >>= 1) {
            s1 += __shfl_xor(s1, off);
            q1 += __shfl_xor(q1, off);
        }
        if (lane == 0) { ls[wave][o] = s1; lq[wave][o] = q1; }
    }
    __syncthreads();
    if (t < 32) {
        psum[blockIdx.x*64 + t] = (ls[0][t]+ls[1][t]) + (ls[2][t]+ls[3][t]);
        psq [blockIdx.x*64 + t] = (lq[0][t]+lq[1][t]) + (lq[2][t]+lq[3][t]);
    }
}

// ============================================================
// 4. fold: partials -> mean/var -> affine {a, c}: act = relu(a*raw + c)
// ============================================================
__global__ void fold_kernel(
    const float* __restrict__ g, const float* __restrict__ be,
    const float* __restrict__ psum, const float* __restrict__ psq,
    float* __restrict__ aff, int Cout)
{
    const int t = threadIdx.x;    // 64 threads
    if (t < Cout) {
        float s = 0.f, q = 0.f;
        for (int i = 0; i < 512; ++i) { s += psum[i*64 + t]; q += psq[i*64 + t]; }
        const float invn = 1.0f / (float)NSITES;
        const float m = s * invn;
        float v2 = fmaxf(q * invn - m*m, 0.f);
        const float a = g[t] * rsqrtf(v2 + 1e-5f);
        aff[t]      = a;
        aff[64 + t] = fmaf(-m, a, be[t]);
    }
}

// ============================================================
// 5. conv1: read raw0, act0 = relu(a0*x+c0) on the fly, conv1 (W1,b1) ->
//    raw1 stored IN PLACE (exclusive 4-site ownership; all loads precede
//    stores) + stats partials.
// ============================================================
__global__ __launch_bounds__(256) void conv1s_kernel(
    const float* x, float* xout,
    const float* __restrict__ aff, const float* __restrict__ W,
    const float* __restrict__ bias,
    float* __restrict__ psum, float* __restrict__ psq)
{
    const int t = threadIdx.x;
    const int v = blockIdx.x*256 + t;
    const int site = v * 4;
    float4 in[32];
    #pragma unroll
    for (int c = 0; c < 32; ++c) {
        float4 r = *reinterpret_cast<const float4*>(x + (size_t)c*NSITES + site);
        const float a = aff[c], cc = aff[64 + c];
        in[c].x = fmaxf(fmaf(a, r.x, cc), 0.f);
        in[c].y = fmaxf(fmaf(a, r.y, cc), 0.f);
        in[c].z = fmaxf(fmaf(a, r.z, cc), 0.f);
        in[c].w = fmaxf(fmaf(a, r.w, cc), 0.f);
    }
    float acc[32], accq[32];
    #pragma unroll
    for (int o = 0; o < 32; ++o) {
        const float bb = bias[o];
        float4 y = make_float4(bb,bb,bb,bb);
        #pragma unroll
        for (int c = 0; c < 32; ++c) {
            const float w = W[o*32+c];
            y.x = fmaf(w, in[c].x, y.x); y.y = fmaf(w, in[c].y, y.y);
            y.z = fmaf(w, in[c].z, y.z); y.w = fmaf(w, in[c].w, y.w);
        }
        *reinterpret_cast<float4*>(xout + (size_t)o*NSITES + site) = y;  // RAW
        acc[o]  = (y.x + y.y) + (y.z + y.w);
        accq[o] = (y.x*y.x + y.y*y.y) + (y.z*y.z + y.w*y.w);
    }
    __shared__ float ls[4][32], lq[4][32];
    const int wave = t>>6, lane = t&63;
    #pragma unroll
    for (int o = 0; o < 32; ++o) {
        float s1 = acc[o], q1 = accq[o];
        #pragma unroll
        for (int off = 32; off >= 1; off >>= 1) {
            s1 += __shfl_xor(s1, off);
            q1 += __shfl_xor(q1, off);
        }
        if (lane == 0) { ls[wave][o] = s1; lq[wave][o] = q1; }
    }
    __syncthreads();
    if (t < 32) {
        psum[blockIdx.x*64 + t] = (ls[0][t]+ls[1][t]) + (ls[2][t]+ls[3][t]);
        psq [blockIdx.x*64 + t] = (lq[0][t]+lq[1][t]) + (lq[2][t]+lq[3][t]);
    }
}

// ============================================================
// 6. conv2 stats: read raw1, act1 on the fly, conv2 (W2,b2) -> stats only.
//    blockIdx.y picks 32-channel half (register pressure).
// ============================================================
__global__ __launch_bounds__(256) void conv2stats_kernel(
    const float* __restrict__ x, const float* __restrict__ aff,
    const float* __restrict__ W, const float* __restrict__ bias,
    float* __restrict__ psum, float* __restrict__ psq)
{
    const int t = threadIdx.x;
    const int v = blockIdx.x*256 + t;
    const int site = v * 4;
    const int coff = blockIdx.y * 32;
    float4 in[32];
    #pragma unroll
    for (int c = 0; c < 32; ++c) {
        float4 r = *reinterpret_cast<const float4*>(x + (size_t)c*NSITES + site);
        const float a = aff[c], cc = aff[64 + c];
        in[c].x = fmaxf(fmaf(a, r.x, cc), 0.f);
        in[c].y = fmaxf(fmaf(a, r.y, cc), 0.f);
        in[c].z = fmaxf(fmaf(a, r.z, cc), 0.f);
        in[c].w = fmaxf(fmaf(a, r.w, cc), 0.f);
    }
    float acc[32], accq[32];
    #pragma unroll
    for (int o = 0; o < 32; ++o) {
        const float bb = bias[coff + o];
        float4 y = make_float4(bb,bb,bb,bb);
        #pragma unroll
        for (int c = 0; c < 32; ++c) {
            const float w = W[(coff+o)*32 + c];
            y.x = fmaf(w, in[c].x, y.x); y.y = fmaf(w, in[c].y, y.y);
            y.z = fmaf(w, in[c].z, y.z); y.w = fmaf(w, in[c].w, y.w);
        }
        acc[o]  = (y.x + y.y) + (y.z + y.w);
        accq[o] = (y.x*y.x + y.y*y.y) + (y.z*y.z + y.w*y.w);
    }
    __shared__ float ls[4][32], lq[4][32];
    const int wave = t>>6, lane = t&63;
    #pragma unroll
    for (int o = 0; o < 32; ++o) {
        float s1 = acc[o], q1 = accq[o];
        #pragma unroll
        for (int off = 32; off >= 1; off >>= 1) {
            s1 += __shfl_xor(s1, off);
            q1 += __shfl_xor(q1, off);
        }
        if (lane == 0) { ls[wave][o] = s1; lq[wave][o] = q1; }
    }
    __syncthreads();
    if (t < 32) {
        psum[blockIdx.x*64 + coff + t] = (ls[0][t]+ls[1][t]) + (ls[2][t]+ls[3][t]);
        psq [blockIdx.x*64 + coff + t] = (lq[0][t]+lq[1][t]) + (lq[2][t]+lq[3][t]);
    }
}

// ============================================================
// 7. conv2 + affine2 + relu + max over k -> output (B,64,S).
//    lane = site; one wave covers 2 (b,s) groups of 32.
// ============================================================
__global__ __launch_bounds__(256) void conv2max_kernel(
    const float* __restrict__ x, const float* __restrict__ aff1,
    const float* __restrict__ aff2, const float* __restrict__ W,
    const float* __restrict__ bias, float* __restrict__ outp)
{
    const int gt = blockIdx.x*256 + threadIdx.x;
    const int wv = gt >> 6;
    const int lane = gt & 63;
    const int base = wv * 64;
    float in[32];
    #pragma unroll
    for (int c = 0; c < 32; ++c) {
        const float r = x[(size_t)c*NSITES + base + lane];
        in[c] = fmaxf(fmaf(aff1[c], r, aff1[64 + c]), 0.f);
    }
    const int bs = (base + lane) >> 5;
    const int b = bs >> 10, s = bs & 1023;
    float* dst = outp + (size_t)b*64*NPOINT + s;
    for (int o = 0; o < 64; ++o) {
        float z = bias[o];
        #pragma unroll
        for (int c = 0; c < 32; ++c)
            z = fmaf(W[o*32+c], in[c], z);
        float y = fmaxf(fmaf(aff2[o], z, aff2[64 + o]), 0.f);
        #pragma unroll
        for (int off = 16; off >= 1; off >>= 1)
            y = fmaxf(y, __shfl_xor(y, off));
        if ((lane & 31) == 0)
            dst[(size_t)o*NPOINT] = y;
    }
}

// ============================================================
extern "C" void kernel_launch(void* const* d_in, const int* in_sizes, int n_in,
                              void* d_out, int out_size, void* d_ws, size_t ws_size,
                              hipStream_t stream) {
    (void)in_sizes; (void)n_in; (void)out_size; (void)ws_size;
    const float* xyz = (const float*)d_in[0];
    const float* pts = (const float*)d_in[1];
    const float* W0  = (const float*)d_in[2];
    const float* b0  = (const float*)d_in[3];
    const float* g0  = (const float*)d_in[4];
    const float* be0 = (const float*)d_in[5];
    const float* W1  = (const float*)d_in[6];
    const float* b1  = (const float*)d_in[7];
    const float* g1  = (const float*)d_in[8];
    const float* be1 = (const float*)d_in[9];
    const float* W2  = (const float*)d_in[10];
    const float* b2  = (const float*)d_in[11];
    const float* g2  = (const float*)d_in[12];
    const float* be2 = (const float*)d_in[13];
    float* out = (float*)d_out;
    char* ws = (char*)d_ws;
    float* nxyz = (float*)(ws + 0);
    int*   gidx = (int*)  (ws + 196608);
    float* psum = (float*)(ws + 2293760);
    float* psq  = (float*)(ws + 2424832);
    float* aff0 = (float*)(ws + 2555904);
    float* aff1 = (float*)(ws + 2556416);
    float* aff2 = (float*)(ws + 2556928);
    float* xbuf = (float*)(ws + 2557440);

    fps_kernel <<<16,  512, 0, stream>>>(xyz, nxyz, out);
    ball_kernel<<<256, 256, 0, stream>>>(xyz, nxyz, gidx);

    conv0s_kernel<<<512, 256, 0, stream>>>(xyz, pts, gidx, nxyz, W0, b0,
                                           xbuf, psum, psq);
    fold_kernel<<<1, 64, 0, stream>>>(g0, be0, psum, psq, aff0, 32);

    conv1s_kernel<<<512, 256, 0, stream>>>(xbuf, xbuf, aff0, W1, b1, psum, psq);
    fold_kernel<<<1, 64, 0, stream>>>(g1, be1, psum, psq, aff1, 32);

    conv2stats_kernel<<<dim3(512,2), 256, 0, stream>>>(xbuf, aff1, W2, b2,
                                                       psum, psq);
    fold_kernel<<<1, 64, 0, stream>>>(g2, be2, psum, psq, aff2, 64);

    conv2max_kernel<<<2048, 256, 0, stream>>>(xbuf, aff1, aff2, W2, b2,
                                              out + 49152);
}

// Round 5
// 958.676 us; speedup vs baseline: 1.5924x; 1.1477x over previous
//
#include <hip/hip_runtime.h>

#define BATCH   16
#define NPTS    4096
#define NPOINT  1024
#define NSAMPLE 32
#define NSITES  (BATCH*NPOINT*NSAMPLE)   // 524288

// ---------------- workspace layout (bytes) ----------------
// nxyz : 0        (196608)
// gidx : 196608   (2097152)
// psum : 2293760  (512*64*4 = 131072)
// psq  : 2424832  (131072)
// aff0 : 2555904  (128 f = 512)   aff = {a[64], c[64]}: act = relu(a*x+c)
// aff1 : 2556416  (512)
// aff2 : 2556928  (512)
// xbuf : 2557440  (64 MB)  -> total ~69.7 MB

// ---------------- DPP wave-64 max (f32), result broadcast via readlane ----
// Canonical gfx9 sequence: row_shr 1/2/4/8 + row_bcast15 + row_bcast31;
// valid in lane 63. ~12 VALU ops vs ~360 cyc of ds_swizzle latency.
__device__ __forceinline__ float wave_max_bcast(float x) {
    int v = __float_as_int(x);
    int t;
    t = __builtin_amdgcn_update_dpp(v, v, 0x111, 0xf, 0xf, false);  // row_shr:1
    v = __float_as_int(fmaxf(__int_as_float(v), __int_as_float(t)));
    t = __builtin_amdgcn_update_dpp(v, v, 0x112, 0xf, 0xf, false);  // row_shr:2
    v = __float_as_int(fmaxf(__int_as_float(v), __int_as_float(t)));
    t = __builtin_amdgcn_update_dpp(v, v, 0x114, 0xf, 0xf, false);  // row_shr:4
    v = __float_as_int(fmaxf(__int_as_float(v), __int_as_float(t)));
    t = __builtin_amdgcn_update_dpp(v, v, 0x118, 0xf, 0xf, false);  // row_shr:8
    v = __float_as_int(fmaxf(__int_as_float(v), __int_as_float(t)));
    t = __builtin_amdgcn_update_dpp(v, v, 0x142, 0xa, 0xf, false);  // row_bcast:15
    v = __float_as_int(fmaxf(__int_as_float(v), __int_as_float(t)));
    t = __builtin_amdgcn_update_dpp(v, v, 0x143, 0xc, 0xf, false);  // row_bcast:31
    v = __float_as_int(fmaxf(__int_as_float(v), __int_as_float(t)));
    return __int_as_float(__builtin_amdgcn_readlane(v, 63));
}

// ============================================================
// 1. FPS: one block/batch, 512 threads, 8 CONTIGUOUS pts/thread in registers
//    (VGPR=40 resident, r4-verified). Reduce: per-thread first-max tree
//    (strict >), DPP wave max + readlane broadcast, ballot -> lowest lane =
//    smallest index, winner packs (val,~idx) u64 -> LDS; 1 barrier; all
//    threads combine 8 keys with a register compare tree (no u64 shuffles).
//    Distance math bit-matches reference (validated rounds 2-4).
// ============================================================
__global__ __launch_bounds__(512, 1) void fps_kernel(
    const float* __restrict__ xyz,   // (B,3,N)
    float* __restrict__ nxyz,        // (B,S,3)
    float* __restrict__ out0)        // (B,3,S)
{
    __shared__ float sx[NPTS], sy[NPTS], sz[NPTS];
    __shared__ int   s_sel[NPOINT];
    __shared__ unsigned long long redK[2][8];

    const int b = blockIdx.x;
    const int t = threadIdx.x;
    const int wave = t >> 6, lane = t & 63;
    const float* xb = xyz + (size_t)b * 3 * NPTS;

    for (int i = t; i < NPTS; i += 512) {
        sx[i] = xb[i]; sy[i] = xb[NPTS+i]; sz[i] = xb[2*NPTS+i];
    }
    __syncthreads();

    const int base = t * 8;
    float px[8], py[8], pz[8], dist[8];
    #pragma unroll
    for (int j = 0; j < 8; ++j) {
        px[j] = sx[base+j]; py[j] = sy[base+j]; pz[j] = sz[base+j];
        dist[j] = 1e10f;
    }

    int far = 0;
    float cx = sx[0], cy = sy[0], cz = sz[0];
    for (int it = 0; it < NPOINT; ++it) {
        if (t == 0) s_sel[it] = far;
        #pragma unroll
        for (int j = 0; j < 8; ++j) {
            const float dx = __fsub_rn(px[j], cx);
            const float dy = __fsub_rn(py[j], cy);
            const float dz = __fsub_rn(pz[j], cz);
            const float d  = __fadd_rn(__fadd_rn(__fmul_rn(dx,dx), __fmul_rn(dy,dy)),
                                       __fmul_rn(dz,dz));
            dist[j] = fminf(dist[j], d);
        }
        // per-thread first-max tree (strict > : earlier index wins ties)
        float tv0, tv1, tv2, tv3; int ti0, ti1, ti2, ti3;
        { bool c = dist[1] > dist[0]; tv0 = c ? dist[1] : dist[0]; ti0 = c ? 1 : 0; }
        { bool c = dist[3] > dist[2]; tv1 = c ? dist[3] : dist[2]; ti1 = c ? 3 : 2; }
        { bool c = dist[5] > dist[4]; tv2 = c ? dist[5] : dist[4]; ti2 = c ? 5 : 4; }
        { bool c = dist[7] > dist[6]; tv3 = c ? dist[7] : dist[6]; ti3 = c ? 7 : 6; }
        float nv0, nv1; int ni0, ni1;
        { bool c = tv1 > tv0; nv0 = c ? tv1 : tv0; ni0 = c ? ti1 : ti0; }
        { bool c = tv3 > tv2; nv1 = c ? tv3 : tv2; ni1 = c ? ti3 : ti2; }
        float bm; int bj;
        { bool c = nv1 > nv0; bm = c ? nv1 : nv0; bj = c ? ni1 : ni0; }
        // DPP wave max, uniform broadcast
        const float M = wave_max_bcast(bm);
        // lowest matching lane == smallest index (contiguous ownership)
        const unsigned long long mask = __ballot(bm == M);
        const int wl = __ffsll(mask) - 1;
        const int par = it & 1;
        if (lane == wl) {
            const unsigned idxg = (unsigned)(base + bj);
            redK[par][wave] = ((unsigned long long)__float_as_uint(M) << 32)
                              | (unsigned)(~idxg);
        }
        __syncthreads();
        // register compare tree over the 8 wave keys (uniform LDS broadcasts)
        const unsigned long long k0 = redK[par][0], k1 = redK[par][1];
        const unsigned long long k2 = redK[par][2], k3 = redK[par][3];
        const unsigned long long k4 = redK[par][4], k5 = redK[par][5];
        const unsigned long long k6 = redK[par][6], k7 = redK[par][7];
        const unsigned long long a0 = (k1 > k0) ? k1 : k0;
        const unsigned long long a1 = (k3 > k2) ? k3 : k2;
        const unsigned long long a2 = (k5 > k4) ? k5 : k4;
        const unsigned long long a3 = (k7 > k6) ? k7 : k6;
        const unsigned long long b0_ = (a1 > a0) ? a1 : a0;
        const unsigned long long b1_ = (a3 > a2) ? a3 : a2;
        const unsigned long long km  = (b1_ > b0_) ? b1_ : b0_;
        far = (int)((~(unsigned)km) & (NPTS-1));
        cx = sx[far]; cy = sy[far]; cz = sz[far];
    }
    __syncthreads();
    for (int s = t; s < NPOINT; s += 512) {
        const int id = s_sel[s];
        const float x = sx[id], y = sy[id], z = sz[id];
        nxyz[((size_t)b*NPOINT + s)*3 + 0] = x;
        nxyz[((size_t)b*NPOINT + s)*3 + 1] = y;
        nxyz[((size_t)b*NPOINT + s)*3 + 2] = z;
        out0[(size_t)b*3*NPOINT + 0*NPOINT + s] = x;
        out0[(size_t)b*3*NPOINT + 1*NPOINT + s] = y;
        out0[(size_t)b*3*NPOINT + 2*NPOINT + s] = z;
    }
}

// ============================================================
// 2. Ball query (validated bit-exact rounds 2-4 — unchanged).
// ============================================================
__global__ __launch_bounds__(256) void ball_kernel(
    const float* __restrict__ xyz, const float* __restrict__ nxyz,
    int* __restrict__ gidx)
{
    __shared__ float sx[NPTS], sy[NPTS], sz[NPTS];
    const int b  = blockIdx.x >> 4;
    const int sg = blockIdx.x & 15;
    const int t = threadIdx.x;
    const int wave = t >> 6, lane = t & 63;
    const float* xb = xyz + (size_t)b * 3 * NPTS;
    for (int i = t; i < NPTS; i += 256) {
        sx[i] = xb[i]; sy[i] = xb[NPTS+i]; sz[i] = xb[2*NPTS+i];
    }
    __syncthreads();
    const unsigned long long lt = (1ull << lane) - 1ull;

    for (int q = wave; q < 64; q += 4) {
        const int s = sg*64 + q;
        const size_t bs = (size_t)b*NPOINT + s;
        const float cx = nxyz[bs*3+0], cy = nxyz[bs*3+1], cz = nxyz[bs*3+2];
        const float ss = __fadd_rn(__fadd_rn(__fmul_rn(cx,cx), __fmul_rn(cy,cy)),
                                   __fmul_rn(cz,cz));
        int* out = gidx + bs*NSAMPLE;
        int cnt = 0;
        int firstIdx = NPTS;
        for (int ch = 0; ch < NPTS/64 && cnt < NSAMPLE; ++ch) {
            const int pi = ch*64 + lane;
            const float qx = sx[pi], qy = sy[pi], qz = sz[pi];
            const float dot = fmaf(cz, qz, fmaf(cy, qy, __fmul_rn(cx, qx)));
            const float sn  = __fadd_rn(__fadd_rn(__fmul_rn(qx,qx), __fmul_rn(qy,qy)),
                                        __fmul_rn(qz,qz));
            const float d   = __fadd_rn(__fadd_rn(__fmul_rn(-2.0f,dot), ss), sn);
            const bool pred = !(d > 0.04f);
            const unsigned long long m = __ballot(pred);
            if (pred) {
                const int pos = cnt + __popcll(m & lt);
                if (pos == 0) firstIdx = pi;
                if (pos < NSAMPLE) out[pos] = pi;
            }
            cnt += (int)__popcll(m);
        }
        if (cnt < NSAMPLE) {
            #pragma unroll
            for (int off = 32; off >= 1; off >>= 1) {
                const int oi = __shfl_xor(firstIdx, off);
                firstIdx = (oi < firstIdx) ? oi : firstIdx;
            }
            for (int p = cnt + lane; p < NSAMPLE; p += 64) out[p] = firstIdx;
        }
    }
}

// ---------------- feature gather (9 ch per site) ----------------
__device__ __forceinline__ void gather_feat(
    const float* __restrict__ xyz, const float* __restrict__ pts,
    const int* __restrict__ gidx, const float* __restrict__ nxyz,
    int v, float4 f[9])
{
    const int site = v * 4;
    const int bs = site >> 5;
    const int b  = bs >> 10;
    const int4 idx = *reinterpret_cast<const int4*>(gidx + site);
    const float* xb = xyz + (size_t)b*3*NPTS;
    const float* pb = pts + (size_t)b*6*NPTS;
    const float cx = nxyz[(size_t)bs*3+0];
    const float cy = nxyz[(size_t)bs*3+1];
    const float cz = nxyz[(size_t)bs*3+2];
    f[0] = make_float4(xb[idx.x]-cx, xb[idx.y]-cx, xb[idx.z]-cx, xb[idx.w]-cx);
    f[1] = make_float4(xb[NPTS+idx.x]-cy, xb[NPTS+idx.y]-cy, xb[NPTS+idx.z]-cy, xb[NPTS+idx.w]-cy);
    f[2] = make_float4(xb[2*NPTS+idx.x]-cz, xb[2*NPTS+idx.y]-cz, xb[2*NPTS+idx.z]-cz, xb[2*NPTS+idx.w]-cz);
    #pragma unroll
    for (int c = 0; c < 6; ++c)
        f[3+c] = make_float4(pb[c*NPTS+idx.x], pb[c*NPTS+idx.y], pb[c*NPTS+idx.z], pb[c*NPTS+idx.w]);
}

// ============================================================
// 3. conv0: ONE gather pass -> raw conv0 (W0,b0) stored + stats partials.
// ============================================================
__global__ __launch_bounds__(256) void conv0s_kernel(
    const float* __restrict__ xyz, const float* __restrict__ pts,
    const int* __restrict__ gidx, const float* __restrict__ nxyz,
    const float* __restrict__ W, const float* __restrict__ bias,
    float* __restrict__ xout, float* __restrict__ psum, float* __restrict__ psq)
{
    const int t = threadIdx.x;
    const int v = blockIdx.x*256 + t;        // 512 blocks -> v < 131072
    const int site = v * 4;
    float4 f[9];
    gather_feat(xyz, pts, gidx, nxyz, v, f);
    float acc[32], accq[32];
    #pragma unroll
    for (int o = 0; o < 32; ++o) {
        const float bb = bias[o];
        float4 y = make_float4(bb,bb,bb,bb);
        #pragma unroll
        for (int c = 0; c < 9; ++c) {
            const float w = W[o*9+c];
            y.x = fmaf(w, f[c].x, y.x); y.y = fmaf(w, f[c].y, y.y);
            y.z = fmaf(w, f[c].z, y.z); y.w = fmaf(w, f[c].w, y.w);
        }
        *reinterpret_cast<float4*>(xout + (size_t)o*NSITES + site) = y;  // RAW
        acc[o]  = (y.x + y.y) + (y.z + y.w);
        accq[o] = (y.x*y.x + y.y*y.y) + (y.z*y.z + y.w*y.w);
    }
    __shared__ float ls[4][32], lq[4][32];
    const int wave = t>>6, lane = t&63;
    #pragma unroll
    for (int o = 0; o < 32; ++o) {
        float s1 = acc[o], q1 = accq[o];
        #pragma unroll
        for (int off = 32; off >= 1; off >>= 1) {
            s1 += __shfl_xor(s1, off);
            q1 += __shfl_xor(q1, off);
        }
        if (lane == 0) { ls[wave][o] = s1; lq[wave][o] = q1; }
    }
    __syncthreads();
    if (t < 32) {
        psum[blockIdx.x*64 + t] = (ls[0][t]+ls[1][t]) + (ls[2][t]+ls[3][t]);
        psq [blockIdx.x*64 + t] = (lq[0][t]+lq[1][t]) + (lq[2][t]+lq[3][t]);
    }
}

// ============================================================
// 4. fold: partials -> mean/var -> affine {a, c}: act = relu(a*raw + c)
// ============================================================
__global__ void fold_kernel(
    const float* __restrict__ g, const float* __restrict__ be,
    const float* __restrict__ psum, const float* __restrict__ psq,
    float* __restrict__ aff, int Cout)
{
    const int t = threadIdx.x;    // 64 threads
    if (t < Cout) {
        float s = 0.f, q = 0.f;
        for (int i = 0; i < 512; ++i) { s += psum[i*64 + t]; q += psq[i*64 + t]; }
        const float invn = 1.0f / (float)NSITES;
        const float m = s * invn;
        float v2 = fmaxf(q * invn - m*m, 0.f);
        const float a = g[t] * rsqrtf(v2 + 1e-5f);
        aff[t]      = a;
        aff[64 + t] = fmaf(-m, a, be[t]);
    }
}

// ============================================================
// 5. conv1: read raw0, act0 = relu(a0*x+c0) on the fly, conv1 (W1,b1) ->
//    raw1 stored IN PLACE + stats partials.
// ============================================================
__global__ __launch_bounds__(256) void conv1s_kernel(
    const float* x, float* xout,
    const float* __restrict__ aff, const float* __restrict__ W,
    const float* __restrict__ bias,
    float* __restrict__ psum, float* __restrict__ psq)
{
    const int t = threadIdx.x;
    const int v = blockIdx.x*256 + t;
    const int site = v * 4;
    float4 in[32];
    #pragma unroll
    for (int c = 0; c < 32; ++c) {
        float4 r = *reinterpret_cast<const float4*>(x + (size_t)c*NSITES + site);
        const float a = aff[c], cc = aff[64 + c];
        in[c].x = fmaxf(fmaf(a, r.x, cc), 0.f);
        in[c].y = fmaxf(fmaf(a, r.y, cc), 0.f);
        in[c].z = fmaxf(fmaf(a, r.z, cc), 0.f);
        in[c].w = fmaxf(fmaf(a, r.w, cc), 0.f);
    }
    float acc[32], accq[32];
    #pragma unroll
    for (int o = 0; o < 32; ++o) {
        const float bb = bias[o];
        float4 y = make_float4(bb,bb,bb,bb);
        #pragma unroll
        for (int c = 0; c < 32; ++c) {
            const float w = W[o*32+c];
            y.x = fmaf(w, in[c].x, y.x); y.y = fmaf(w, in[c].y, y.y);
            y.z = fmaf(w, in[c].z, y.z); y.w = fmaf(w, in[c].w, y.w);
        }
        *reinterpret_cast<float4*>(xout + (size_t)o*NSITES + site) = y;  // RAW
        acc[o]  = (y.x + y.y) + (y.z + y.w);
        accq[o] = (y.x*y.x + y.y*y.y) + (y.z*y.z + y.w*y.w);
    }
    __shared__ float ls[4][32], lq[4][32];
    const int wave = t>>6, lane = t&63;
    #pragma unroll
    for (int o = 0; o < 32; ++o) {
        float s1 = acc[o], q1 = accq[o];
        #pragma unroll
        for (int off = 32; off >= 1; off >>= 1) {
            s1 += __shfl_xor(s1, off);
            q1 += __shfl_xor(q1, off);
        }
        if (lane == 0) { ls[wave][o] = s1; lq[wave][o] = q1; }
    }
    __syncthreads();
    if (t < 32) {
        psum[blockIdx.x*64 + t] = (ls[0][t]+ls[1][t]) + (ls[2][t]+ls[3][t]);
        psq [blockIdx.x*64 + t] = (lq[0][t]+lq[1][t]) + (lq[2][t]+lq[3][t]);
    }
}

// ============================================================
// 6. conv2 stats: read raw1, act1 on the fly, conv2 (W2,b2) -> stats only.
//    blockIdx.y picks 32-channel half (register pressure).
// ============================================================
__global__ __launch_bounds__(256) void conv2stats_kernel(
    const float* __restrict__ x, const float* __restrict__ aff,
    const float* __restrict__ W, const float* __restrict__ bias,
    float* __restrict__ psum, float* __restrict__ psq)
{
    const int t = threadIdx.x;
    const int v = blockIdx.x*256 + t;
    const int site = v * 4;
    const int coff = blockIdx.y * 32;
    float4 in[32];
    #pragma unroll
    for (int c = 0; c < 32; ++c) {
        float4 r = *reinterpret_cast<const float4*>(x + (size_t)c*NSITES + site);
        const float a = aff[c], cc = aff[64 + c];
        in[c].x = fmaxf(fmaf(a, r.x, cc), 0.f);
        in[c].y = fmaxf(fmaf(a, r.y, cc), 0.f);
        in[c].z = fmaxf(fmaf(a, r.z, cc), 0.f);
        in[c].w = fmaxf(fmaf(a, r.w, cc), 0.f);
    }
    float acc[32], accq[32];
    #pragma unroll
    for (int o = 0; o < 32; ++o) {
        const float bb = bias[coff + o];
        float4 y = make_float4(bb,bb,bb,bb);
        #pragma unroll
        for (int c = 0; c < 32; ++c) {
            const float w = W[(coff+o)*32 + c];
            y.x = fmaf(w, in[c].x, y.x); y.y = fmaf(w, in[c].y, y.y);
            y.z = fmaf(w, in[c].z, y.z); y.w = fmaf(w, in[c].w, y.w);
        }
        acc[o]  = (y.x + y.y) + (y.z + y.w);
        accq[o] = (y.x*y.x + y.y*y.y) + (y.z*y.z + y.w*y.w);
    }
    __shared__ float ls[4][32], lq[4][32];
    const int wave = t>>6, lane = t&63;
    #pragma unroll
    for (int o = 0; o < 32; ++o) {
        float s1 = acc[o], q1 = accq[o];
        #pragma unroll
        for (int off = 32; off >= 1; off >>= 1) {
            s1 += __shfl_xor(s1, off);
            q1 += __shfl_xor(q1, off);
        }
        if (lane == 0) { ls[wave][o] = s1; lq[wave][o] = q1; }
    }
    __syncthreads();
    if (t < 32) {
        psum[blockIdx.x*64 + coff + t] = (ls[0][t]+ls[1][t]) + (ls[2][t]+ls[3][t]);
        psq [blockIdx.x*64 + coff + t] = (lq[0][t]+lq[1][t]) + (lq[2][t]+lq[3][t]);
    }
}

// ============================================================
// 7. conv2 + affine2 + relu + max over k -> output (B,64,S).
// ============================================================
__global__ __launch_bounds__(256) void conv2max_kernel(
    const float* __restrict__ x, const float* __restrict__ aff1,
    const float* __restrict__ aff2, const float* __restrict__ W,
    const float* __restrict__ bias, float* __restrict__ outp)
{
    const int gt = blockIdx.x*256 + threadIdx.x;
    const int wv = gt >> 6;
    const int lane = gt & 63;
    const int base = wv * 64;
    float in[32];
    #pragma unroll
    for (int c = 0; c < 32; ++c) {
        const float r = x[(size_t)c*NSITES + base + lane];
        in[c] = fmaxf(fmaf(aff1[c], r, aff1[64 + c]), 0.f);
    }
    const int bs = (base + lane) >> 5;
    const int b = bs >> 10, s = bs & 1023;
    float* dst = outp + (size_t)b*64*NPOINT + s;
    for (int o = 0; o < 64; ++o) {
        float z = bias[o];
        #pragma unroll
        for (int c = 0; c < 32; ++c)
            z = fmaf(W[o*32+c], in[c], z);
        float y = fmaxf(fmaf(aff2[o], z, aff2[64 + o]), 0.f);
        #pragma unroll
        for (int off = 16; off >= 1; off >>= 1)
            y = fmaxf(y, __shfl_xor(y, off));
        if ((lane & 31) == 0)
            dst[(size_t)o*NPOINT] = y;
    }
}

// ============================================================
extern "C" void kernel_launch(void* const* d_in, const int* in_sizes, int n_in,
                              void* d_out, int out_size, void* d_ws, size_t ws_size,
                              hipStream_t stream) {
    (void)in_sizes; (void)n_in; (void)out_size; (void)ws_size;
    const float* xyz = (const float*)d_in[0];
    const float* pts = (const float*)d_in[1];
    const float* W0  = (const float*)d_in[2];
    const float* b0  = (const float*)d_in[3];
    const float* g0  = (const float*)d_in[4];
    const float* be0 = (const float*)d_in[5];
    const float* W1  = (const float*)d_in[6];
    const float* b1  = (const float*)d_in[7];
    const float* g1  = (const float*)d_in[8];
    const float* be1 = (const float*)d_in[9];
    const float* W2  = (const float*)d_in[10];
    const float* b2  = (const float*)d_in[11];
    const float* g2  = (const float*)d_in[12];
    const float* be2 = (const float*)d_in[13];
    float* out = (float*)d_out;
    char* ws = (char*)d_ws;
    float* nxyz = (float*)(ws + 0);
    int*   gidx = (int*)  (ws + 196608);
    float* psum = (float*)(ws + 2293760);
    float* psq  = (float*)(ws + 2424832);
    float* aff0 = (float*)(ws + 2555904);
    float* aff1 = (float*)(ws + 2556416);
    float* aff2 = (float*)(ws + 2556928);
    float* xbuf = (float*)(ws + 2557440);

    fps_kernel <<<16,  512, 0, stream>>>(xyz, nxyz, out);
    ball_kernel<<<256, 256, 0, stream>>>(xyz, nxyz, gidx);

    conv0s_kernel<<<512, 256, 0, stream>>>(xyz, pts, gidx, nxyz, W0, b0,
                                           xbuf, psum, psq);
    fold_kernel<<<1, 64, 0, stream>>>(g0, be0, psum, psq, aff0, 32);

    conv1s_kernel<<<512, 256, 0, stream>>>(xbuf, xbuf, aff0, W1, b1, psum, psq);
    fold_kernel<<<1, 64, 0, stream>>>(g1, be1, psum, psq, aff1, 32);

    conv2stats_kernel<<<dim3(512,2), 256, 0, stream>>>(xbuf, aff1, W2, b2,
                                                       psum, psq);
    fold_kernel<<<1, 64, 0, stream>>>(g2, be2, psum, psq, aff2, 64);

    conv2max_kernel<<<2048, 256, 0, stream>>>(xbuf, aff1, aff2, W2, b2,
                                              out + 49152);
}